// Round 9
// baseline (133.808 us; speedup 1.0000x reference)
//
#include <hip/hip_runtime.h>

#define NB 4
#define NQ 128
#define NK 1024
#define NH 256
#define NE 256
#define NV 256

#define TSCALE 2.8853900817779268f  // 2*log2(e)
#define LOG2E  1.4426950408889634f

static __device__ __forceinline__ float fexp2(float x){ return __builtin_amdgcn_exp2f(x); }
static __device__ __forceinline__ float frcp (float x){ return __builtin_amdgcn_rcpf(x); }
static __device__ __forceinline__ float tanh_of(float x){
    float e = fexp2(x * TSCALE);
    return fmaf(-2.0f, frcp(e + 1.0f), 1.0f);
}

// ---------------- proj: blocks [0,128): q-side (4 rows each) -> qdatA/qdatB packed
//                        blocks [128,640): k-side (8 rows each) -> kTt tiled
// kTt float4 index: ((b*16 + c)*64 + h4)*64 + kl   (c = k>>6, kl = k&63)
__global__ __launch_bounds__(256) void proj_kernel(
    const float* __restrict__ qin, const float* __restrict__ kin,
    const float* __restrict__ Wq, const float* __restrict__ Wk,
    const float* __restrict__ Wv,
    float4* __restrict__ qdatA, float4* __restrict__ qdatB,
    float4* __restrict__ kTt) {
    const int tid = threadIdx.x;
    const int bi  = blockIdx.x;
    __shared__ float tr[NH][9];
    if (bi < NB * 32) {
        const int row0 = bi * 4;
        const float* r0 = qin + row0 * NE;
        float a0 = 0.f, a1 = 0.f, a2 = 0.f, a3 = 0.f;
#pragma unroll 2
        for (int e = 0; e < NE; e += 4) {
            float4 q0 = *(const float4*)(r0 + e);
            float4 q1 = *(const float4*)(r0 + NE + e);
            float4 q2 = *(const float4*)(r0 + 2 * NE + e);
            float4 q3 = *(const float4*)(r0 + 3 * NE + e);
#pragma unroll
            for (int j = 0; j < 4; ++j) {
                float w = Wq[(e + j) * NH + tid];
                a0 = fmaf(((const float*)&q0)[j], w, a0);
                a1 = fmaf(((const float*)&q1)[j], w, a1);
                a2 = fmaf(((const float*)&q2)[j], w, a2);
                a3 = fmaf(((const float*)&q3)[j], w, a3);
            }
        }
        float wv = Wv[tid];
        float t0 = tanh_of(a0), t1 = tanh_of(a1), t2 = tanh_of(a2), t3 = tanh_of(a3);
        qdatA[bi * NH + tid] = make_float4(t0, wv * t0, t1, wv * t1);
        qdatB[bi * NH + tid] = make_float4(t2, wv * t2, t3, wv * t3);
    } else {
        const int kb = bi - NB * 32;
        const int b  = kb >> 7;
        const int k0 = (kb & 127) * 8;
        const int c   = k0 >> 6;
        const int kl0 = k0 & 63;
        const float* kr = kin + (b * NK + k0) * NE;
        float acc[8] = {0.f,0.f,0.f,0.f,0.f,0.f,0.f,0.f};
#pragma unroll 2
        for (int e = 0; e < NE; e += 4) {
            float4 kvv[8];
#pragma unroll
            for (int i = 0; i < 8; ++i) kvv[i] = *(const float4*)(kr + i * NE + e);
#pragma unroll
            for (int j = 0; j < 4; ++j) {
                float w = Wk[(e + j) * NH + tid];
#pragma unroll
                for (int i = 0; i < 8; ++i)
                    acc[i] = fmaf(((const float*)&kvv[i])[j], w, acc[i]);
            }
        }
#pragma unroll
        for (int i = 0; i < 8; ++i) tr[tid][i] = tanh_of(acc[i]);
        __syncthreads();
#pragma unroll
        for (int p = 0; p < 2; ++p) {
            int idx2 = p * 256 + tid;
            int hg = idx2 >> 3;
            int kk = idx2 & 7;
            float4 v = make_float4(tr[hg*4+0][kk], tr[hg*4+1][kk],
                                   tr[hg*4+2][kk], tr[hg*4+3][kk]);
            kTt[((b * 16 + c) * 64 + hg) * 64 + kl0 + kk] = v;
        }
    }
}

// ---------------- fused attention, 8 q-rows per block (2 qq-groups):
// halves the kTt/V tile re-read volume vs 4-row blocks.
// blockIdx = jj*8 + xcd; qg = jj&15; gs = (jj>>4)*8 + xcd (XCD-local groups).
__global__ __launch_bounds__(256) void attn_kernel(
    const float4* __restrict__ qdatA, const float4* __restrict__ qdatB,
    const float4* __restrict__ kTt, const float* __restrict__ V,
    const int* __restrict__ vlen, const float4* __restrict__ Wv4,
    float* __restrict__ part_m, float* __restrict__ part_s,
    float* __restrict__ part_pv) {
    const int tid = threadIdx.x, lane = tid & 63, wvid = tid >> 6;
    const int n0 = (vlen[0] + 63) >> 6, n1 = (vlen[1] + 63) >> 6;
    const int n2 = (vlen[2] + 63) >> 6, n3 = (vlen[3] + 63) >> 6;
    const int G  = n0 + n1 + n2 + n3;       // valid (b,chunk) groups (<=64)
    const int bi = blockIdx.x;
    const int xcd = bi & 7;
    const int jj  = bi >> 3;
    const int qg  = jj & 15;                // q-octet 0..15
    const int gs  = ((jj >> 4) << 3) + xcd; // group slot; gs%8 == xcd
    if (gs >= G) return;
    int b, chunk;
    if      (gs < n0)           { b = 0; chunk = gs; }
    else if (gs < n0 + n1)      { b = 1; chunk = gs - n0; }
    else if (gs < n0 + n1 + n2) { b = 2; chunk = gs - n0 - n1; }
    else                        { b = 3; chunk = gs - n0 - n1 - n2; }
    const int vl    = vlen[b];
    const int k0    = chunk * 64;
    const int k     = k0 + lane;
    const int pidx  = (b * 16 + qg) * 16 + chunk;
    float* pm  = part_m + pidx * 8;
    float* ps  = part_s + pidx * 8;
    float* ppv = part_pv + pidx * (8 * NV);

    // LDS: phase A h-partials (stride 9), then PV partials (stride 33) — union
    __shared__ float ldsbuf[4][64 * 33];   // 33 KB
    __shared__ float pwS[8][64];           // softmax weights [row][k-lane]

    const int qq0 = qg * 2, qq1 = qg * 2 + 1;
    const float4* qA0 = qdatA + (b * 32 + qq0) * NH;  // wave-uniform
    const float4* qB0 = qdatB + (b * 32 + qq0) * NH;
    const float4* qA1 = qdatA + (b * 32 + qq1) * NH;
    const float4* qB1 = qdatB + (b * 32 + qq1) * NH;

    // phase A: wave wvid reads contiguous 16KB window (rows h4 = wvid*16..+16)
    const float4* kp = kTt + ((b * 16 + chunk) * 64 + wvid * 16) * 64 + lane;
    float acc[8] = {0.f,0.f,0.f,0.f,0.f,0.f,0.f,0.f};
#pragma unroll 4
    for (int i = 0; i < 16; ++i) {
        float4 kv4 = kp[i * 64];          // sequential 1KB wave-loads
        const int h4 = wvid * 16 + i;
        float4 wv4 = Wv4[h4];
#pragma unroll
        for (int j = 0; j < 4; ++j) {
            float kv  = (j==0)?kv4.x:(j==1)?kv4.y:(j==2)?kv4.z:kv4.w;
            float wvj = (j==0)?wv4.x:(j==1)?wv4.y:(j==2)?wv4.z:wv4.w;
            float wvb = wvj * kv;
            float4 qa0 = qA0[h4 * 4 + j], qb0 = qB0[h4 * 4 + j];
            float4 qa1 = qA1[h4 * 4 + j], qb1 = qB1[h4 * 4 + j];
            float p0 = fmaf(qa0.x, kv, 1.0f), u0 = qa0.y + wvb;
            float p1 = fmaf(qa0.z, kv, 1.0f), u1 = qa0.w + wvb;
            float p2 = fmaf(qb0.x, kv, 1.0f), u2 = qb0.y + wvb;
            float p3 = fmaf(qb0.z, kv, 1.0f), u3 = qb0.w + wvb;
            float p4 = fmaf(qa1.x, kv, 1.0f), u4 = qa1.y + wvb;
            float p5 = fmaf(qa1.z, kv, 1.0f), u5 = qa1.w + wvb;
            float p6 = fmaf(qb1.x, kv, 1.0f), u6 = qb1.y + wvb;
            float p7 = fmaf(qb1.z, kv, 1.0f), u7 = qb1.w + wvb;
            // ONE rcp for 8 reciprocals
            float a  = p0 * p1, bb = p2 * p3, c = p4 * p5, d = p6 * p7;
            float ab = a * bb,  cd = c * d;
            float r  = frcp(ab * cd);
            float rab = r * cd, rcd = r * ab;      // 1/(p0p1p2p3), 1/(p4p5p6p7)
            float ia = rab * bb, ib = rab * a;     // 1/(p0p1), 1/(p2p3)
            float ic = rcd * d,  id = rcd * c;     // 1/(p4p5), 1/(p6p7)
            acc[0] = fmaf(u0, ia * p1, acc[0]);
            acc[1] = fmaf(u1, ia * p0, acc[1]);
            acc[2] = fmaf(u2, ib * p3, acc[2]);
            acc[3] = fmaf(u3, ib * p2, acc[3]);
            acc[4] = fmaf(u4, ic * p5, acc[4]);
            acc[5] = fmaf(u5, ic * p4, acc[5]);
            acc[6] = fmaf(u6, id * p7, acc[6]);
            acc[7] = fmaf(u7, id * p6, acc[7]);
        }
    }
    {
        float* hp = &ldsbuf[wvid][lane * 9];
#pragma unroll
        for (int r = 0; r < 8; ++r) hp[r] = acc[r];
    }
    __syncthreads();
    // cross-wave h-reduce + softmax: wave wvid handles rows wvid*2, wvid*2+1
    {
#pragma unroll
        for (int rr = 0; rr < 2; ++rr) {
            const int row = wvid * 2 + rr;
            float s = ldsbuf[0][lane * 9 + row] + ldsbuf[1][lane * 9 + row]
                    + ldsbuf[2][lane * 9 + row] + ldsbuf[3][lane * 9 + row];
            s = (k < vl) ? s : -1e30f;
            float m = s;
#pragma unroll
            for (int d = 32; d >= 1; d >>= 1) m = fmaxf(m, __shfl_xor(m, d, 64));
            float p = fexp2((s - m) * LOG2E);     // masked -> exactly 0
            float u = p;
#pragma unroll
            for (int d = 32; d >= 1; d >>= 1) u += __shfl_xor(u, d, 64);
            if (lane == 0) { pm[row] = m; ps[row] = u; }
            pwS[row][lane] = p;
        }
    }
    __syncthreads();
    // phase B: PV — wave wvid covers kk in [wvid*16, wvid*16+16), all 8 rows
    {
        const float* Vb = V + (b * NK + k0) * NV;
        const int v4 = lane * 4;
        float4 o[8];
#pragma unroll
        for (int r = 0; r < 8; ++r) o[r] = make_float4(0.f, 0.f, 0.f, 0.f);
#pragma unroll 4
        for (int kk = 0; kk < 16; ++kk) {
            const int kkk = wvid * 16 + kk;
            float4 vv = *(const float4*)&Vb[kkk * NV + v4];
#pragma unroll
            for (int r = 0; r < 8; ++r) {
                float p = pwS[r][kkk];            // uniform -> broadcast
                o[r].x = fmaf(p, vv.x, o[r].x);
                o[r].y = fmaf(p, vv.y, o[r].y);
                o[r].z = fmaf(p, vv.z, o[r].z);
                o[r].w = fmaf(p, vv.w, o[r].w);
            }
        }
        float* pd = &ldsbuf[wvid][lane * 33];
#pragma unroll
        for (int r = 0; r < 8; ++r) {
            pd[r * 4 + 0] = o[r].x; pd[r * 4 + 1] = o[r].y;
            pd[r * 4 + 2] = o[r].z; pd[r * 4 + 3] = o[r].w;
        }
    }
    __syncthreads();
    {
        const int vg = tid & 63;
#pragma unroll
        for (int rr = 0; rr < 2; ++rr) {
            const int row = rr * 4 + (tid >> 6);
            float4 r4 = {0,0,0,0};
#pragma unroll
            for (int ww = 0; ww < 4; ++ww) {
                const float* ps2 = &ldsbuf[ww][vg * 33 + row * 4];
                r4.x += ps2[0]; r4.y += ps2[1]; r4.z += ps2[2]; r4.w += ps2[3];
            }
            *(float4*)&ppv[row * NV + vg * 4] = r4;
        }
    }
}

// ---------------- combine: 512 blocks — one (b, qg, row) each (row 0..7)
__global__ __launch_bounds__(256) void combine_kernel(
    const float* __restrict__ part_m, const float* __restrict__ part_s,
    const float* __restrict__ part_pv, const int* __restrict__ vlen,
    float* __restrict__ out) {
    const int tid = threadIdx.x;
    const int idx = blockIdx.x;     // 0..511
    const int row = idx & 7;
    const int qg  = (idx >> 3) & 15;
    const int b   = idx >> 7;
    const int nb  = (vlen[b] + 63) >> 6;    // valid chunks (1..16)
    const int base = (b * 16 + qg) * 16;
    float M = -1e30f;
    for (int q = 0; q < nb; ++q)
        M = fmaxf(M, part_m[(base + q) * 8 + row]);
    float S = 0.f, o = 0.f;
    for (int q = 0; q < nb; ++q) {
        float wq = fexp2((part_m[(base + q) * 8 + row] - M) * LOG2E);
        S = fmaf(part_s[(base + q) * 8 + row], wq, S);
        o = fmaf(part_pv[((base + q) * 8 + row) * NV + tid], wq, o);
    }
    const int qq = qg * 2 + (row >> 2);
    out[((b * 32 + qq) * 4 + (row & 3)) * NV + tid] = o * frcp(S);
}

extern "C" void kernel_launch(void* const* d_in, const int* in_sizes, int n_in,
                              void* d_out, int out_size, void* d_ws, size_t ws_size,
                              hipStream_t stream) {
    const float* queries = (const float*)d_in[0];
    const float* keys    = (const float*)d_in[1];
    const float* values  = (const float*)d_in[2];
    const int*   vlens   = (const int*)  d_in[3];
    const float* Wq      = (const float*)d_in[4];
    const float* Wk      = (const float*)d_in[5];
    const float* Wv      = (const float*)d_in[6];
    float* out = (float*)d_out;

    float4* qdatA  = (float4*)d_ws;                  // 32768 float4 (512 KB)
    float4* qdatB  = qdatA + NB * 32 * NH;           // 32768 float4 (512 KB)
    float4* kTt    = qdatB + NB * 32 * NH;           // 262144 float4 (4 MB, tiled)
    float*  part_m = (float*)(kTt + NB * 64 * NK);   // 16384 floats
    float*  part_s = part_m + 16384;                 // 16384 floats
    float*  part_pv = part_s + 16384;                // 8M floats (32 MB)

    proj_kernel   <<<dim3(640), dim3(256), 0, stream>>>(queries, keys, Wq, Wk, Wv,
                                                        qdatA, qdatB, kTt);
    attn_kernel   <<<dim3(1024), dim3(256), 0, stream>>>(qdatA, qdatB, kTt, values,
                                                         vlens, (const float4*)Wv,
                                                         part_m, part_s, part_pv);
    combine_kernel<<<dim3(512), dim3(256), 0, stream>>>(part_m, part_s, part_pv,
                                                        vlens, out);
}

// Round 10
// 118.807 us; speedup vs baseline: 1.1263x; 1.1263x over previous
//
#include <hip/hip_runtime.h>

#define NB 4
#define NQ 128
#define NK 1024
#define NH 256
#define NE 256
#define NV 256

#define TSCALE 2.8853900817779268f  // 2*log2(e)
#define LOG2E  1.4426950408889634f

static __device__ __forceinline__ float fexp2(float x){ return __builtin_amdgcn_exp2f(x); }
static __device__ __forceinline__ float frcp (float x){ return __builtin_amdgcn_rcpf(x); }
static __device__ __forceinline__ float tanh_of(float x){
    float e = fexp2(x * TSCALE);
    return fmaf(-2.0f, frcp(e + 1.0f), 1.0f);
}

// ---------------- proj: blocks [0,128): q-side (4 rows each) -> qdatA/qdatB packed
//                        blocks [128,640): k-side (8 rows each) -> kTt tiled
// kTt float4 index: ((b*16 + c)*64 + h4)*64 + kl   (c = k>>6, kl = k&63)
__global__ __launch_bounds__(256) void proj_kernel(
    const float* __restrict__ qin, const float* __restrict__ kin,
    const float* __restrict__ Wq, const float* __restrict__ Wk,
    const float* __restrict__ Wv,
    float4* __restrict__ qdatA, float4* __restrict__ qdatB,
    float4* __restrict__ kTt) {
    const int tid = threadIdx.x;
    const int bi  = blockIdx.x;
    __shared__ float tr[NH][9];
    if (bi < NB * 32) {
        const int row0 = bi * 4;
        const float* r0 = qin + row0 * NE;
        float a0 = 0.f, a1 = 0.f, a2 = 0.f, a3 = 0.f;
#pragma unroll 2
        for (int e = 0; e < NE; e += 4) {
            float4 q0 = *(const float4*)(r0 + e);
            float4 q1 = *(const float4*)(r0 + NE + e);
            float4 q2 = *(const float4*)(r0 + 2 * NE + e);
            float4 q3 = *(const float4*)(r0 + 3 * NE + e);
#pragma unroll
            for (int j = 0; j < 4; ++j) {
                float w = Wq[(e + j) * NH + tid];
                a0 = fmaf(((const float*)&q0)[j], w, a0);
                a1 = fmaf(((const float*)&q1)[j], w, a1);
                a2 = fmaf(((const float*)&q2)[j], w, a2);
                a3 = fmaf(((const float*)&q3)[j], w, a3);
            }
        }
        float wv = Wv[tid];
        float t0 = tanh_of(a0), t1 = tanh_of(a1), t2 = tanh_of(a2), t3 = tanh_of(a3);
        qdatA[bi * NH + tid] = make_float4(t0, wv * t0, t1, wv * t1);
        qdatB[bi * NH + tid] = make_float4(t2, wv * t2, t3, wv * t3);
    } else {
        const int kb = bi - NB * 32;
        const int b  = kb >> 7;
        const int k0 = (kb & 127) * 8;
        const int c   = k0 >> 6;
        const int kl0 = k0 & 63;
        const float* kr = kin + (b * NK + k0) * NE;
        float acc[8] = {0.f,0.f,0.f,0.f,0.f,0.f,0.f,0.f};
#pragma unroll 2
        for (int e = 0; e < NE; e += 4) {
            float4 kvv[8];
#pragma unroll
            for (int i = 0; i < 8; ++i) kvv[i] = *(const float4*)(kr + i * NE + e);
#pragma unroll
            for (int j = 0; j < 4; ++j) {
                float w = Wk[(e + j) * NH + tid];
#pragma unroll
                for (int i = 0; i < 8; ++i)
                    acc[i] = fmaf(((const float*)&kvv[i])[j], w, acc[i]);
            }
        }
#pragma unroll
        for (int i = 0; i < 8; ++i) tr[tid][i] = tanh_of(acc[i]);
        __syncthreads();
#pragma unroll
        for (int p = 0; p < 2; ++p) {
            int idx2 = p * 256 + tid;
            int hg = idx2 >> 3;
            int kk = idx2 & 7;
            float4 v = make_float4(tr[hg*4+0][kk], tr[hg*4+1][kk],
                                   tr[hg*4+2][kk], tr[hg*4+3][kk]);
            kTt[((b * 16 + c) * 64 + hg) * 64 + kl0 + kk] = v;
        }
    }
}

// ---------------- fused attention (R8 structure; q-feed moved scalar -> LDS):
// block = (b,chunk,qq) via XCD swizzle; 4 q-rows; wave wvid owns h-quarter.
// q-data (8 KB) staged into LDS once; hot loop reads broadcast ds_read_b128.
__global__ __launch_bounds__(256) void attn_kernel(
    const float4* __restrict__ qdatA, const float4* __restrict__ qdatB,
    const float4* __restrict__ kTt, const float* __restrict__ V,
    const int* __restrict__ vlen, const float4* __restrict__ Wv4,
    float* __restrict__ part_m, float* __restrict__ part_s,
    float* __restrict__ part_pv) {
    const int tid = threadIdx.x, lane = tid & 63, wvid = tid >> 6;
    const int n0 = (vlen[0] + 63) >> 6, n1 = (vlen[1] + 63) >> 6;
    const int n2 = (vlen[2] + 63) >> 6, n3 = (vlen[3] + 63) >> 6;
    const int G  = n0 + n1 + n2 + n3;       // valid (b,chunk) groups (<=64)
    const int bi = blockIdx.x;
    const int xcd = bi & 7;
    const int jj  = bi >> 3;
    const int qq  = jj & 31;
    const int gs  = ((jj >> 5) << 3) + xcd; // group slot; gs%8 == xcd
    if (gs >= G) return;
    int b, chunk;
    if      (gs < n0)           { b = 0; chunk = gs; }
    else if (gs < n0 + n1)      { b = 1; chunk = gs - n0; }
    else if (gs < n0 + n1 + n2) { b = 2; chunk = gs - n0 - n1; }
    else                        { b = 3; chunk = gs - n0 - n1 - n2; }
    const int vl    = vlen[b];
    const int k0    = chunk * 64;
    const int k     = k0 + lane;
    const int pidx  = (b * 32 + qq) * 16 + chunk;
    float* pm  = part_m + pidx * 4;
    float* ps  = part_s + pidx * 4;
    float* ppv = part_pv + pidx * (4 * NV);

    __shared__ float red17[4][64 * 17];   // phase A: h-partials; phase B: pv-partials
    __shared__ float pwS[4][64];          // softmax weights, [q-row][k-lane]
    __shared__ float4 qLA[NH], qLB[NH];   // staged q-data (8 KB)

    // stage q-data once: coalesced 16 B/lane vector loads
    qLA[tid] = qdatA[(b * 32 + qq) * NH + tid];
    qLB[tid] = qdatB[(b * 32 + qq) * NH + tid];
    __syncthreads();

    // phase A: wave wvid reads contiguous 16KB window (rows h4 = wvid*16..+16)
    const float4* kp = kTt + ((b * 16 + chunk) * 64 + wvid * 16) * 64 + lane;
    float acc0 = 0.f, acc1 = 0.f, acc2 = 0.f, acc3 = 0.f;
#pragma unroll
    for (int i = 0; i < 16; ++i) {
        float4 kv4 = kp[i * 64];          // sequential 1KB wave-loads, deep-hoisted
        const int h4 = wvid * 16 + i;
        float4 wv4 = Wv4[h4];             // sK$-hot (1 KB shared device-wide)
#pragma unroll
        for (int j = 0; j < 4; ++j) {
            float kv  = (j==0)?kv4.x:(j==1)?kv4.y:(j==2)?kv4.z:kv4.w;
            float wvj = (j==0)?wv4.x:(j==1)?wv4.y:(j==2)?wv4.z:wv4.w;
            float wvb = wvj * kv;
            float4 qa = qLA[h4 * 4 + j];  // broadcast ds_read_b128, conflict-free
            float4 qb = qLB[h4 * 4 + j];
            float p0 = fmaf(qa.x, kv, 1.0f), nu0 = qa.y + wvb;
            float p1 = fmaf(qa.z, kv, 1.0f), nu1 = qa.w + wvb;
            float p2 = fmaf(qb.x, kv, 1.0f), nu2 = qb.y + wvb;
            float p3 = fmaf(qb.z, kv, 1.0f), nu3 = qb.w + wvb;
            float ab = p0 * p1, cd = p2 * p3;
            float r  = frcp(ab * cd);
            float rab = r * cd, rcd = r * ab;
            acc0 = fmaf(nu0, rab * p1, acc0);
            acc1 = fmaf(nu1, rab * p0, acc1);
            acc2 = fmaf(nu2, rcd * p3, acc2);
            acc3 = fmaf(nu3, rcd * p2, acc3);
        }
    }
    {
        float* hp = &red17[wvid][lane * 17];
        hp[0] = acc0; hp[1] = acc1; hp[2] = acc2; hp[3] = acc3;
    }
    __syncthreads();
    // cross-wave h-reduce; wave = q-row, lane = k-lane
    {
        const int row = wvid;
        float s = red17[0][lane * 17 + row] + red17[1][lane * 17 + row]
                + red17[2][lane * 17 + row] + red17[3][lane * 17 + row];
        s = (k < vl) ? s : -1e30f;
        float m = s;
#pragma unroll
        for (int d = 32; d >= 1; d >>= 1) m = fmaxf(m, __shfl_xor(m, d, 64));
        float p = fexp2((s - m) * LOG2E);     // masked -> exactly 0
        float u = p;
#pragma unroll
        for (int d = 32; d >= 1; d >>= 1) u += __shfl_xor(u, d, 64);
        if (lane == 0) { pm[row] = m; ps[row] = u; }
        pwS[row][lane] = p;
    }
    __syncthreads();
    // phase B: PV — wave wvid covers kk in [wvid*16, wvid*16+16), all 4 q-rows
    {
        const float* Vb = V + (b * NK + k0) * NV;
        const int v4 = lane * 4;
        float4 o0 = {0,0,0,0}, o1 = {0,0,0,0}, o2 = {0,0,0,0}, o3 = {0,0,0,0};
#pragma unroll 4
        for (int kk = 0; kk < 16; ++kk) {
            const int kkk = wvid * 16 + kk;
            float p0 = pwS[0][kkk], p1 = pwS[1][kkk];   // uniform -> broadcast
            float p2 = pwS[2][kkk], p3 = pwS[3][kkk];
            float4 vv = *(const float4*)&Vb[kkk * NV + v4];
            o0.x = fmaf(p0, vv.x, o0.x); o0.y = fmaf(p0, vv.y, o0.y);
            o0.z = fmaf(p0, vv.z, o0.z); o0.w = fmaf(p0, vv.w, o0.w);
            o1.x = fmaf(p1, vv.x, o1.x); o1.y = fmaf(p1, vv.y, o1.y);
            o1.z = fmaf(p1, vv.z, o1.z); o1.w = fmaf(p1, vv.w, o1.w);
            o2.x = fmaf(p2, vv.x, o2.x); o2.y = fmaf(p2, vv.y, o2.y);
            o2.z = fmaf(p2, vv.z, o2.z); o2.w = fmaf(p2, vv.w, o2.w);
            o3.x = fmaf(p3, vv.x, o3.x); o3.y = fmaf(p3, vv.y, o3.y);
            o3.z = fmaf(p3, vv.z, o3.z); o3.w = fmaf(p3, vv.w, o3.w);
        }
        float* pd = &red17[wvid][lane * 17];
        *(float4*)(pd + 0)  = o0;
        *(float4*)(pd + 4)  = o1;
        *(float4*)(pd + 8)  = o2;
        *(float4*)(pd + 12) = o3;
    }
    __syncthreads();
    {
        const int row = tid >> 6, vg = tid & 63;
        float4 r = {0,0,0,0};
#pragma unroll
        for (int ww = 0; ww < 4; ++ww) {
            float4 t = *(const float4*)&red17[ww][vg * 17 + row * 4];
            r.x += t.x; r.y += t.y; r.z += t.z; r.w += t.w;
        }
        *(float4*)&ppv[row * NV + vg * 4] = r;
    }
}

// ---------------- combine: 512 blocks — one (b*32+qq, q-row) each
__global__ __launch_bounds__(256) void combine_kernel(
    const float* __restrict__ part_m, const float* __restrict__ part_s,
    const float* __restrict__ part_pv, const int* __restrict__ vlen,
    float* __restrict__ out) {
    const int tid = threadIdx.x;
    const int idx = blockIdx.x;     // 0..511
    const int bi  = idx >> 2;       // b*32+qq
    const int i   = idx & 3;        // q-row within group
    const int b   = bi >> 5;
    const int nb  = (vlen[b] + 63) >> 6;    // valid chunks (1..16)
    const int base = bi * 16;
    float M = -1e30f;
    for (int q = 0; q < nb; ++q)
        M = fmaxf(M, part_m[(base + q) * 4 + i]);
    float S = 0.f, o = 0.f;
    for (int q = 0; q < nb; ++q) {
        float wq = fexp2((part_m[(base + q) * 4 + i] - M) * LOG2E);
        S = fmaf(part_s[(base + q) * 4 + i], wq, S);
        o = fmaf(part_pv[((base + q) * 4 + i) * NV + tid], wq, o);
    }
    out[(bi * 4 + i) * NV + tid] = o * frcp(S);
}

extern "C" void kernel_launch(void* const* d_in, const int* in_sizes, int n_in,
                              void* d_out, int out_size, void* d_ws, size_t ws_size,
                              hipStream_t stream) {
    const float* queries = (const float*)d_in[0];
    const float* keys    = (const float*)d_in[1];
    const float* values  = (const float*)d_in[2];
    const int*   vlens   = (const int*)  d_in[3];
    const float* Wq      = (const float*)d_in[4];
    const float* Wk      = (const float*)d_in[5];
    const float* Wv      = (const float*)d_in[6];
    float* out = (float*)d_out;

    float4* qdatA  = (float4*)d_ws;                  // 32768 float4 (512 KB)
    float4* qdatB  = qdatA + NB * 32 * NH;           // 32768 float4 (512 KB)
    float4* kTt    = qdatB + NB * 32 * NH;           // 262144 float4 (4 MB, tiled)
    float*  part_m = (float*)(kTt + NB * 64 * NK);   // 8192 floats
    float*  part_s = part_m + 8192;                  // 8192 floats
    float*  part_pv = part_s + 8192;                 // 2M floats (8 MB)

    proj_kernel   <<<dim3(640), dim3(256), 0, stream>>>(queries, keys, Wq, Wk, Wv,
                                                        qdatA, qdatB, kTt);
    attn_kernel   <<<dim3(2048), dim3(256), 0, stream>>>(qdatA, qdatB, kTt, values,
                                                         vlens, (const float4*)Wv,
                                                         part_m, part_s, part_pv);
    combine_kernel<<<dim3(512), dim3(256), 0, stream>>>(part_m, part_s, part_pv,
                                                        vlens, out);
}

// Round 11
// 113.131 us; speedup vs baseline: 1.1828x; 1.0502x over previous
//
#include <hip/hip_runtime.h>

#define NB 4
#define NQ 128
#define NK 1024
#define NH 256
#define NE 256
#define NV 256

#define TSCALE 2.8853900817779268f  // 2*log2(e)
#define LOG2E  1.4426950408889634f

static __device__ __forceinline__ float fexp2(float x){ return __builtin_amdgcn_exp2f(x); }
static __device__ __forceinline__ float frcp (float x){ return __builtin_amdgcn_rcpf(x); }
static __device__ __forceinline__ float tanh_of(float x){
    float e = fexp2(x * TSCALE);
    return fmaf(-2.0f, frcp(e + 1.0f), 1.0f);
}

// ---------------- proj: blocks [0,128): q-side (4 rows each) -> qTa packed
//                        blocks [128,640): k-side (8 rows each) -> kTt tiled
// qTa[(b*32+qq)*256+h] = (Ta_r0, Ta_r1, Ta_r2, Ta_r3)   (4 KB per (b,qq))
// kTt float4 index: ((b*16 + c)*64 + h4)*64 + kl   (c = k>>6, kl = k&63)
__global__ __launch_bounds__(256) void proj_kernel(
    const float* __restrict__ qin, const float* __restrict__ kin,
    const float* __restrict__ Wq, const float* __restrict__ Wk,
    const float* __restrict__ Wv,
    float4* __restrict__ qTa, float4* __restrict__ kTt) {
    const int tid = threadIdx.x;
    const int bi  = blockIdx.x;
    __shared__ float tr[NH][9];
    if (bi < NB * 32) {
        const int row0 = bi * 4;
        const float* r0 = qin + row0 * NE;
        float a0 = 0.f, a1 = 0.f, a2 = 0.f, a3 = 0.f;
#pragma unroll 2
        for (int e = 0; e < NE; e += 4) {
            float4 q0 = *(const float4*)(r0 + e);
            float4 q1 = *(const float4*)(r0 + NE + e);
            float4 q2 = *(const float4*)(r0 + 2 * NE + e);
            float4 q3 = *(const float4*)(r0 + 3 * NE + e);
#pragma unroll
            for (int j = 0; j < 4; ++j) {
                float w = Wq[(e + j) * NH + tid];
                a0 = fmaf(((const float*)&q0)[j], w, a0);
                a1 = fmaf(((const float*)&q1)[j], w, a1);
                a2 = fmaf(((const float*)&q2)[j], w, a2);
                a3 = fmaf(((const float*)&q3)[j], w, a3);
            }
        }
        qTa[bi * NH + tid] = make_float4(tanh_of(a0), tanh_of(a1),
                                         tanh_of(a2), tanh_of(a3));
    } else {
        const int kb = bi - NB * 32;
        const int b  = kb >> 7;
        const int k0 = (kb & 127) * 8;
        const int c   = k0 >> 6;
        const int kl0 = k0 & 63;
        const float* kr = kin + (b * NK + k0) * NE;
        float acc[8] = {0.f,0.f,0.f,0.f,0.f,0.f,0.f,0.f};
#pragma unroll 2
        for (int e = 0; e < NE; e += 4) {
            float4 kvv[8];
#pragma unroll
            for (int i = 0; i < 8; ++i) kvv[i] = *(const float4*)(kr + i * NE + e);
#pragma unroll
            for (int j = 0; j < 4; ++j) {
                float w = Wk[(e + j) * NH + tid];
#pragma unroll
                for (int i = 0; i < 8; ++i)
                    acc[i] = fmaf(((const float*)&kvv[i])[j], w, acc[i]);
            }
        }
#pragma unroll
        for (int i = 0; i < 8; ++i) tr[tid][i] = tanh_of(acc[i]);
        __syncthreads();
#pragma unroll
        for (int p = 0; p < 2; ++p) {
            int idx2 = p * 256 + tid;
            int hg = idx2 >> 3;
            int kk = idx2 & 7;
            float4 v = make_float4(tr[hg*4+0][kk], tr[hg*4+1][kk],
                                   tr[hg*4+2][kk], tr[hg*4+3][kk]);
            kTt[((b * 16 + c) * 64 + hg) * 64 + kl0 + kk] = v;
        }
    }
}

// ---------------- fused attention (R10 structure; LDS instr count halved):
// score term: wv*tanh(qp+kp) = wv*(Ta+Tb) / (1+Ta*Tb), wv folded into the
// batched reciprocal -> ONE ds_read_b128 per j-step (was two).
__global__ __launch_bounds__(256) void attn_kernel(
    const float4* __restrict__ qTa,
    const float4* __restrict__ kTt, const float* __restrict__ V,
    const int* __restrict__ vlen, const float4* __restrict__ Wv4,
    float* __restrict__ part_m, float* __restrict__ part_s,
    float* __restrict__ part_pv) {
    const int tid = threadIdx.x, lane = tid & 63, wvid = tid >> 6;
    const int n0 = (vlen[0] + 63) >> 6, n1 = (vlen[1] + 63) >> 6;
    const int n2 = (vlen[2] + 63) >> 6, n3 = (vlen[3] + 63) >> 6;
    const int G  = n0 + n1 + n2 + n3;       // valid (b,chunk) groups (<=64)
    const int bi = blockIdx.x;
    const int xcd = bi & 7;
    const int jj  = bi >> 3;
    const int qq  = jj & 31;
    const int gs  = ((jj >> 5) << 3) + xcd; // group slot; gs%8 == xcd
    if (gs >= G) return;
    int b, chunk;
    if      (gs < n0)           { b = 0; chunk = gs; }
    else if (gs < n0 + n1)      { b = 1; chunk = gs - n0; }
    else if (gs < n0 + n1 + n2) { b = 2; chunk = gs - n0 - n1; }
    else                        { b = 3; chunk = gs - n0 - n1 - n2; }
    const int vl    = vlen[b];
    const int k0    = chunk * 64;
    const int k     = k0 + lane;
    const int pidx  = (b * 32 + qq) * 16 + chunk;
    float* pm  = part_m + pidx * 4;
    float* ps  = part_s + pidx * 4;
    float* ppv = part_pv + pidx * (4 * NV);

    __shared__ float red17[4][64 * 17];   // phase A: h-partials; phase B: pv-partials
    __shared__ float pwT[64][4];          // softmax weights TRANSPOSED [k-lane][row]
    __shared__ float4 qL[NH];             // staged Ta4 (4 KB)

    // stage q-data once: coalesced 16 B/lane vector loads
    qL[tid] = qTa[(b * 32 + qq) * NH + tid];
    __syncthreads();

    // phase A: wave wvid reads contiguous 16KB window (rows h4 = wvid*16..+16)
    const float4* kp = kTt + ((b * 16 + chunk) * 64 + wvid * 16) * 64 + lane;
    float acc0 = 0.f, acc1 = 0.f, acc2 = 0.f, acc3 = 0.f;
#pragma unroll
    for (int i = 0; i < 16; ++i) {
        float4 kv4 = kp[i * 64];          // sequential 1KB wave-loads, deep-hoisted
        const int h4 = wvid * 16 + i;
        float4 wv4 = Wv4[h4];             // sK$-hot (1 KB shared device-wide)
#pragma unroll
        for (int j = 0; j < 4; ++j) {
            float kv  = (j==0)?kv4.x:(j==1)?kv4.y:(j==2)?kv4.z:kv4.w;
            float wvj = (j==0)?wv4.x:(j==1)?wv4.y:(j==2)?wv4.z:wv4.w;
            float4 qa = qL[h4 * 4 + j];   // ONE broadcast ds_read_b128
            float p0 = fmaf(qa.x, kv, 1.0f), t0 = qa.x + kv;
            float p1 = fmaf(qa.y, kv, 1.0f), t1 = qa.y + kv;
            float p2 = fmaf(qa.z, kv, 1.0f), t2 = qa.z + kv;
            float p3 = fmaf(qa.w, kv, 1.0f), t3 = qa.w + kv;
            float ab = p0 * p1, cd = p2 * p3;
            float rw = wvj * frcp(ab * cd);   // wv folded into batched rcp
            float rab = rw * cd, rcd = rw * ab;
            acc0 = fmaf(t0, rab * p1, acc0);
            acc1 = fmaf(t1, rab * p0, acc1);
            acc2 = fmaf(t2, rcd * p3, acc2);
            acc3 = fmaf(t3, rcd * p2, acc3);
        }
    }
    {
        float* hp = &red17[wvid][lane * 17];
        hp[0] = acc0; hp[1] = acc1; hp[2] = acc2; hp[3] = acc3;
    }
    __syncthreads();
    // cross-wave h-reduce; wave = q-row, lane = k-lane
    {
        const int row = wvid;
        float s = red17[0][lane * 17 + row] + red17[1][lane * 17 + row]
                + red17[2][lane * 17 + row] + red17[3][lane * 17 + row];
        s = (k < vl) ? s : -1e30f;
        float m = s;
#pragma unroll
        for (int d = 32; d >= 1; d >>= 1) m = fmaxf(m, __shfl_xor(m, d, 64));
        float p = fexp2((s - m) * LOG2E);     // masked -> exactly 0
        float u = p;
#pragma unroll
        for (int d = 32; d >= 1; d >>= 1) u += __shfl_xor(u, d, 64);
        if (lane == 0) { pm[row] = m; ps[row] = u; }
        pwT[lane][row] = p;                   // transposed store (8-way, 4 instrs total)
    }
    __syncthreads();
    // phase B: PV — wave wvid covers kk in [wvid*16, wvid*16+16), all 4 q-rows;
    // weights arrive as ONE b128 broadcast per kk (was four b32).
    {
        const float* Vb = V + (b * NK + k0) * NV;
        const int v4 = lane * 4;
        float4 o0 = {0,0,0,0}, o1 = {0,0,0,0}, o2 = {0,0,0,0}, o3 = {0,0,0,0};
#pragma unroll 4
        for (int kk = 0; kk < 16; ++kk) {
            const int kkk = wvid * 16 + kk;
            float4 pv = *(const float4*)&pwT[kkk][0];   // b128 broadcast
            float4 vv = *(const float4*)&Vb[kkk * NV + v4];
            o0.x = fmaf(pv.x, vv.x, o0.x); o0.y = fmaf(pv.x, vv.y, o0.y);
            o0.z = fmaf(pv.x, vv.z, o0.z); o0.w = fmaf(pv.x, vv.w, o0.w);
            o1.x = fmaf(pv.y, vv.x, o1.x); o1.y = fmaf(pv.y, vv.y, o1.y);
            o1.z = fmaf(pv.y, vv.z, o1.z); o1.w = fmaf(pv.y, vv.w, o1.w);
            o2.x = fmaf(pv.z, vv.x, o2.x); o2.y = fmaf(pv.z, vv.y, o2.y);
            o2.z = fmaf(pv.z, vv.z, o2.z); o2.w = fmaf(pv.z, vv.w, o2.w);
            o3.x = fmaf(pv.w, vv.x, o3.x); o3.y = fmaf(pv.w, vv.y, o3.y);
            o3.z = fmaf(pv.w, vv.z, o3.z); o3.w = fmaf(pv.w, vv.w, o3.w);
        }
        float* pd = &red17[wvid][lane * 17];
        *(float4*)(pd + 0)  = o0;
        *(float4*)(pd + 4)  = o1;
        *(float4*)(pd + 8)  = o2;
        *(float4*)(pd + 12) = o3;
    }
    __syncthreads();
    {
        const int row = tid >> 6, vg = tid & 63;
        float4 r = {0,0,0,0};
#pragma unroll
        for (int ww = 0; ww < 4; ++ww) {
            float4 t = *(const float4*)&red17[ww][vg * 17 + row * 4];
            r.x += t.x; r.y += t.y; r.z += t.z; r.w += t.w;
        }
        *(float4*)&ppv[row * NV + vg * 4] = r;
    }
}

// ---------------- combine: 512 blocks — one (b*32+qq, q-row) each
__global__ __launch_bounds__(256) void combine_kernel(
    const float* __restrict__ part_m, const float* __restrict__ part_s,
    const float* __restrict__ part_pv, const int* __restrict__ vlen,
    float* __restrict__ out) {
    const int tid = threadIdx.x;
    const int idx = blockIdx.x;     // 0..511
    const int bi  = idx >> 2;       // b*32+qq
    const int i   = idx & 3;        // q-row within group
    const int b   = bi >> 5;
    const int nb  = (vlen[b] + 63) >> 6;    // valid chunks (1..16)
    const int base = bi * 16;
    float M = -1e30f;
    for (int q = 0; q < nb; ++q)
        M = fmaxf(M, part_m[(base + q) * 4 + i]);
    float S = 0.f, o = 0.f;
    for (int q = 0; q < nb; ++q) {
        float wq = fexp2((part_m[(base + q) * 4 + i] - M) * LOG2E);
        S = fmaf(part_s[(base + q) * 4 + i], wq, S);
        o = fmaf(part_pv[((base + q) * 4 + i) * NV + tid], wq, o);
    }
    out[(bi * 4 + i) * NV + tid] = o * frcp(S);
}

extern "C" void kernel_launch(void* const* d_in, const int* in_sizes, int n_in,
                              void* d_out, int out_size, void* d_ws, size_t ws_size,
                              hipStream_t stream) {
    const float* queries = (const float*)d_in[0];
    const float* keys    = (const float*)d_in[1];
    const float* values  = (const float*)d_in[2];
    const int*   vlens   = (const int*)  d_in[3];
    const float* Wq      = (const float*)d_in[4];
    const float* Wk      = (const float*)d_in[5];
    const float* Wv      = (const float*)d_in[6];
    float* out = (float*)d_out;

    float4* qTa    = (float4*)d_ws;                  // 32768 float4 (512 KB)
    float4* kTt    = qTa + NB * 32 * NH;             // 262144 float4 (4 MB, tiled)
    float*  part_m = (float*)(kTt + NB * 64 * NK);   // 8192 floats
    float*  part_s = part_m + 8192;                  // 8192 floats
    float*  part_pv = part_s + 8192;                 // 2M floats (8 MB)

    proj_kernel   <<<dim3(640), dim3(256), 0, stream>>>(queries, keys, Wq, Wk, Wv,
                                                        qTa, kTt);
    attn_kernel   <<<dim3(2048), dim3(256), 0, stream>>>(qTa, kTt, values,
                                                         vlens, (const float4*)Wv,
                                                         part_m, part_s, part_pv);
    combine_kernel<<<dim3(512), dim3(256), 0, stream>>>(part_m, part_s, part_pv,
                                                        vlens, out);
}